// Round 7
// baseline (116.121 us; speedup 1.0000x reference)
//
#include <hip/hip_runtime.h>

#define RANK 16
#define N 512

typedef float vfloat4 __attribute__((ext_vector_type(4)));

__global__ __launch_bounds__(256) void parafac_kernel(
    const float* __restrict__ f0,
    const float* __restrict__ f1,
    const float* __restrict__ f2,
    float* __restrict__ out)
{
    __shared__ float pt[RANK][N];        // full rank-product table for this a: 32 KB

    const int t    = threadIdx.x;
    const int wave = t >> 6;             // 0..3
    const int lane = t & 63;
    const int a    = blockIdx.x;         // one a-slice (1 MB contiguous output) per block

    // ---- Stage pt[k][b] = f0[k][a] * f1[k][b] for ALL b (once per block) ----
    // thread -> k = t>>4, b = (t&15)*4 + j*64  (8 vfloat4 per thread, conflict-free)
    {
        const int sk   = t >> 4;
        const int sbi0 = (t & 15) * 4;
        const float s  = f0[sk * N + a];
#pragma unroll
        for (int j = 0; j < 8; ++j) {
            const int sbi = sbi0 + j * 64;
            const vfloat4 f1v = *reinterpret_cast<const vfloat4*>(&f1[sk * N + sbi]);
            *reinterpret_cast<vfloat4*>(&pt[sk][sbi]) = s * f1v;
        }
    }

    // ---- f2 fragment resident in registers: 16 x float4 (64 VGPRs), loaded once ----
    const int c4 = (wave & 1) * 256 + lane * 4;   // wave pair covers full c-row
    vfloat4 v[RANK];
#pragma unroll
    for (int k = 0; k < RANK; ++k)
        v[k] = *reinterpret_cast<const vfloat4*>(&f2[k * N + c4]);

    __syncthreads();   // the only barrier in the kernel

    // ---- Wave group (wave>>1) owns b-half; rows advance monotonically ----
    const int bhalf = (wave >> 1) * 256;          // rows 0..255 or 256..511
    float* outa = out + (size_t)a * N * N + c4;

#pragma unroll 2
    for (int it = 0; it < 64; ++it) {
        const int bb = bhalf + it * 4;
        vfloat4 acc0 = (vfloat4)(0.f);
        vfloat4 acc1 = (vfloat4)(0.f);
        vfloat4 acc2 = (vfloat4)(0.f);
        vfloat4 acc3 = (vfloat4)(0.f);
#pragma unroll
        for (int k = 0; k < RANK; ++k) {
            const vfloat4 pk = *reinterpret_cast<const vfloat4*>(&pt[k][bb]); // broadcast
            const vfloat4 vk = v[k];
            acc0 += pk.x * vk;
            acc1 += pk.y * vk;
            acc2 += pk.z * vk;
            acc3 += pk.w * vk;
        }
        float* o = outa + (size_t)bb * N;
        *reinterpret_cast<vfloat4*>(o)         = acc0;
        *reinterpret_cast<vfloat4*>(o + N)     = acc1;
        *reinterpret_cast<vfloat4*>(o + 2 * N) = acc2;
        *reinterpret_cast<vfloat4*>(o + 3 * N) = acc3;
    }
}

extern "C" void kernel_launch(void* const* d_in, const int* in_sizes, int n_in,
                              void* d_out, int out_size, void* d_ws, size_t ws_size,
                              hipStream_t stream) {
    const float* f0 = (const float*)d_in[0];
    const float* f1 = (const float*)d_in[1];
    const float* f2 = (const float*)d_in[2];
    float* out = (float*)d_out;

    dim3 grid(N);       // 512 blocks, one per a; 2 blocks/CU
    dim3 block(256);
    parafac_kernel<<<grid, block, 0, stream>>>(f0, f1, f2, out);
}

// Round 8
// 106.907 us; speedup vs baseline: 1.0862x; 1.0862x over previous
//
#include <hip/hip_runtime.h>

#define RANK 16
#define N 512
#define ROWS 256            // b-rows per block (contiguous 512 KB output slab)

typedef float vfloat4 __attribute__((ext_vector_type(4)));

__global__ __launch_bounds__(256) void parafac_kernel(
    const float* __restrict__ f0,
    const float* __restrict__ f1,
    const float* __restrict__ f2,
    float* __restrict__ out)
{
    // b-major rank-product table: pt[r][k], r = row within block's slab. 16 KB.
    __shared__ float pt[ROWS][RANK];

    const int t    = threadIdx.x;
    const int wave = t >> 6;             // 0..3
    const int lane = t & 63;
    const int blk  = blockIdx.x;         // 1024 blocks
    const int a    = blk >> 1;           // each a is split into two b-halves
    const int bb0  = (blk & 1) * ROWS;   // b-half base

    // ---- Stage pt[r][k] = f0[k][a] * f1[k][bb0+r]; thread t -> row t ----
    {
        const int b = bb0 + t;
#pragma unroll
        for (int k = 0; k < RANK; ++k)
            pt[t][k] = f0[k * N + a] * f1[k * N + b];
    }

    // ---- f2 fragment in registers: 16 x float4 (64 VGPRs), c-half per wave ----
    const int c4 = (wave & 1) * 256 + lane * 4;
    vfloat4 v[RANK];
#pragma unroll
    for (int k = 0; k < RANK; ++k)
        v[k] = *reinterpret_cast<const vfloat4*>(&f2[k * N + c4]);

    __syncthreads();   // only barrier

    // ---- 128 iterations: 4 waves write 2 complete consecutive rows (4 KB),
    //      block sweeps its 512 KB slab strictly monotonically ----
    const int rofs = wave >> 1;          // 0 or 1: which of the 2 rows this iter
    float* outb = out + ((size_t)a * N + bb0) * N + c4;

#pragma unroll 2
    for (int it = 0; it < ROWS / 2; ++it) {
        const int r = it * 2 + rofs;
        // 16 rank products for this row: 4 broadcast ds_read_b128
        vfloat4 p0 = *reinterpret_cast<const vfloat4*>(&pt[r][0]);
        vfloat4 p1 = *reinterpret_cast<const vfloat4*>(&pt[r][4]);
        vfloat4 p2 = *reinterpret_cast<const vfloat4*>(&pt[r][8]);
        vfloat4 p3 = *reinterpret_cast<const vfloat4*>(&pt[r][12]);

        vfloat4 acc = (vfloat4)(0.f);
#pragma unroll
        for (int j = 0; j < 4; ++j) {
            acc += p0[j] * v[j];
            acc += p1[j] * v[4 + j];
            acc += p2[j] * v[8 + j];
            acc += p3[j] * v[12 + j];
        }
        *reinterpret_cast<vfloat4*>(outb + (size_t)r * N) = acc;
    }
}

extern "C" void kernel_launch(void* const* d_in, const int* in_sizes, int n_in,
                              void* d_out, int out_size, void* d_ws, size_t ws_size,
                              hipStream_t stream) {
    const float* f0 = (const float*)d_in[0];
    const float* f1 = (const float*)d_in[1];
    const float* f2 = (const float*)d_in[2];
    float* out = (float*)d_out;

    dim3 grid(N * 2);   // 1024 blocks: (a, b-half); 4 blocks/CU, 16 waves/CU
    dim3 block(256);
    parafac_kernel<<<grid, block, 0, stream>>>(f0, f1, f2, out);
}